// Round 4
// baseline (154.997 us; speedup 1.0000x reference)
//
#include <hip/hip_runtime.h>
#include <math.h>

// Chamfer p-norm loss (P=5), B=8, N=M=4096, C=3.
// R4 theory: rounds 1-3 were LDS-READ-bound (1 ds_read_b128 per (wave,ref) pair
// = ~115K cyc/CU = the 50 us floor). Fix: register-block QPT=4 queries/thread
// -> 4x LDS amortization. Inner loop: 3 v_pk_fma_f32 per 2 refs per query,
// v_min3 tree per 8-ref group, group-id tracking only. Exact index recovered
// once at the end by re-scanning the winning 8-ref group from GLOBAL R
// (L1-resident, bit-identical fma chain) -> no divergent-LDS bank conflicts.
// Scores made positive by folding +64 into h (free) -> u64 pack needs no ord
// transform. Cross-split combine: plain per-split store slices + counter
// handshake; gather + finalize fused. 2 dispatches total.

#define BQ      256
#define QPT     4
#define SPLITS  16
#define CH      256           // refs per split-block
#define NG      (CH / 8)      // 32 groups of 8 refs
#define BIGOFF  64.0f         // makes all scores positive: |q|^2 < 128 always

typedef float f32x2 __attribute__((ext_vector_type(2)));

__device__ __forceinline__ f32x2 mk2(float s) { f32x2 v; v.x = s; v.y = s; return v; }
__device__ __forceinline__ f32x2 fma2(f32x2 a, f32x2 b, f32x2 c) {
    return __builtin_elementwise_fma(a, b, c);
}
__device__ __forceinline__ unsigned int float_ord(float f) {
    unsigned int u = __float_as_uint(f);
    return (u & 0x80000000u) ? ~u : (u | 0x80000000u);
}

// ws layout (primary): [0,64) acc[16] | [64,320) tcnt u32[64] | [320,324) fcnt
//                      [4096, 4096+8MB) part: u64[SPLITS][65536]
#define WS_ACC   0
#define WS_TCNT  64
#define WS_FCNT  320
#define WS_PART  4096

__global__ __launch_bounds__(BQ) void chamfer_r4(
    const float* __restrict__ x, const float* __restrict__ y,
    unsigned char* __restrict__ ws, float* __restrict__ out)
{
    __shared__ float4 sref[CH];   // pair layout: [2p]=(rx0,rx1,ry0,ry1) [2p+1]=(rz0,rz1,h0,h1)
    __shared__ float red[4];
    __shared__ int s_last;

    float* acc = (float*)(ws + WS_ACC);
    unsigned int* tcnt = (unsigned int*)(ws + WS_TCNT);
    unsigned int* fcnt = (unsigned int*)(ws + WS_FCNT);
    unsigned long long* part = (unsigned long long*)(ws + WS_PART);

    const int bid   = blockIdx.x;
    const int split = bid & (SPLITS - 1);
    const int tq    = bid >> 4;            // 0..63 = dir*32 + b*4 + t4
    const int dir   = tq >> 5;
    const int b     = (tq >> 2) & 7;
    const int t4    = tq & 3;

    const float* Q; const float* R;
    if (dir == 0) { Q = x + (size_t)b * 4096 * 3; R = y + (size_t)b * 4096 * 3; }
    else          { Q = y + (size_t)b * 4096 * 3; R = x + (size_t)b * 4096 * 3; }

    const int tid = threadIdx.x;

    // ---- stage CH refs into LDS (pair layout, h = |r|^2/2 + 64 folded in)
    if (tid < CH / 2) {
        const float* rp = R + (size_t)(split * CH + 2 * tid) * 3;
        const float f0 = rp[0], f1 = rp[1], f2 = rp[2];
        const float f3 = rp[3], f4 = rp[4], f5 = rp[5];
        const float h0 = fmaf(0.5f * f0, f0, fmaf(0.5f * f1, f1, fmaf(0.5f * f2, f2, BIGOFF)));
        const float h1 = fmaf(0.5f * f3, f3, fmaf(0.5f * f4, f4, fmaf(0.5f * f5, f5, BIGOFF)));
        sref[2 * tid]     = make_float4(f0, f3, f1, f4);
        sref[2 * tid + 1] = make_float4(f2, f5, h0, h1);
    }

    // ---- load QPT queries per thread (coalesced: stride-256 within the 1024-query tile)
    float qx[QPT], qy[QPT], qz[QPT];
    #pragma unroll
    for (int i = 0; i < QPT; ++i) {
        const int ql = t4 * 1024 + i * 256 + tid;
        qx[i] = Q[ql * 3 + 0]; qy[i] = Q[ql * 3 + 1]; qz[i] = Q[ql * 3 + 2];
    }
    __syncthreads();

    f32x2 nqx[QPT], nqy[QPT], nqz[QPT];
    #pragma unroll
    for (int i = 0; i < QPT; ++i) { nqx[i] = mk2(-qx[i]); nqy[i] = mk2(-qy[i]); nqz[i] = mk2(-qz[i]); }

    float best[QPT]; int bestg[QPT];
    #pragma unroll
    for (int i = 0; i < QPT; ++i) { best[i] = 3.4e38f; bestg[i] = 0; }

    // ---- main scan: 32 groups of 8 refs; per group per query: 12 pk_fma + min3 tree + track
    #pragma unroll 2
    for (int g = 0; g < NG; ++g) {
        const float4 a0 = sref[g * 8 + 0], c0 = sref[g * 8 + 1];
        const float4 a1 = sref[g * 8 + 2], c1 = sref[g * 8 + 3];
        const float4 a2 = sref[g * 8 + 4], c2 = sref[g * 8 + 5];
        const float4 a3 = sref[g * 8 + 6], c3 = sref[g * 8 + 7];
        f32x2 rx0, ry0, rz0, h0; rx0.x=a0.x; rx0.y=a0.y; ry0.x=a0.z; ry0.y=a0.w; rz0.x=c0.x; rz0.y=c0.y; h0.x=c0.z; h0.y=c0.w;
        f32x2 rx1, ry1, rz1, h1; rx1.x=a1.x; rx1.y=a1.y; ry1.x=a1.z; ry1.y=a1.w; rz1.x=c1.x; rz1.y=c1.y; h1.x=c1.z; h1.y=c1.w;
        f32x2 rx2, ry2, rz2, h2; rx2.x=a2.x; rx2.y=a2.y; ry2.x=a2.z; ry2.y=a2.w; rz2.x=c2.x; rz2.y=c2.y; h2.x=c2.z; h2.y=c2.w;
        f32x2 rx3, ry3, rz3, h3; rx3.x=a3.x; rx3.y=a3.y; ry3.x=a3.z; ry3.y=a3.w; rz3.x=c3.x; rz3.y=c3.y; h3.x=c3.z; h3.y=c3.w;
        #pragma unroll
        for (int i = 0; i < QPT; ++i) {
            const f32x2 t0 = fma2(nqx[i], rx0, fma2(nqy[i], ry0, fma2(nqz[i], rz0, h0)));
            const f32x2 t1 = fma2(nqx[i], rx1, fma2(nqy[i], ry1, fma2(nqz[i], rz1, h1)));
            const f32x2 t2 = fma2(nqx[i], rx2, fma2(nqy[i], ry2, fma2(nqz[i], rz2, h2)));
            const f32x2 t3 = fma2(nqx[i], rx3, fma2(nqy[i], ry3, fma2(nqz[i], rz3, h3)));
            const float m = fminf(fminf(fminf(t0.x, t0.y), fminf(t1.x, t1.y)),
                                  fminf(fminf(t2.x, t2.y), fminf(t3.x, t3.y)));
            const bool c = m < best[i];        // strict <: earliest group on ties
            best[i]  = c ? m : best[i];
            bestg[i] = c ? g : bestg[i];
        }
    }

    // ---- exact index: re-scan winning 8-ref group from GLOBAL R (L1-resident,
    //      bit-identical fma/h chain reproduces the LDS-path score exactly)
    #pragma unroll
    for (int i = 0; i < QPT; ++i) {
        const int basej = split * CH + bestg[i] * 8;
        int bj = basej;
        #pragma unroll
        for (int j = 7; j >= 0; --j) {        // descending: smallest j wins ties
            const float* rp = R + (size_t)(basej + j) * 3;
            const float rx = rp[0], ry = rp[1], rz = rp[2];
            const float h = fmaf(0.5f * rx, rx, fmaf(0.5f * ry, ry, fmaf(0.5f * rz, rz, BIGOFF)));
            const float s = fmaf(-qx[i], rx, fmaf(-qy[i], ry, fmaf(-qz[i], rz, h)));
            if (s == best[i]) bj = basej + j;
        }
        const size_t qidx = (size_t)tq * 1024 + i * 256 + tid;
        part[(size_t)split * 65536 + qidx] =
            ((unsigned long long)__float_as_uint(best[i]) << 32) | (unsigned int)bj;
    }

    // ---- handshake: last split block of this tile gathers
    __syncthreads();
    if (tid == 0) {
        __threadfence();
        s_last = (atomicAdd(&tcnt[tq], 1u) == SPLITS - 1);
    }
    __syncthreads();
    if (!s_last) return;
    __threadfence();

    float ssum = 0.0f;
    #pragma unroll
    for (int i = 0; i < QPT; ++i) {
        const size_t qidx = (size_t)tq * 1024 + i * 256 + tid;
        unsigned long long w = ~0ull;
        for (int s = 0; s < SPLITS; ++s) {
            const unsigned long long v = __hip_atomic_load(
                &part[(size_t)s * 65536 + qidx], __ATOMIC_RELAXED, __HIP_MEMORY_SCOPE_AGENT);
            w = (v < w) ? v : w;              // positive scores: u64 order == (score, j) order
        }
        const int j = (int)(unsigned int)w;
        const float dx = qx[i] - R[(size_t)j * 3 + 0];
        const float dy = qy[i] - R[(size_t)j * 3 + 1];
        const float dz = qz[i] - R[(size_t)j * 3 + 2];
        const float ax = fabsf(dx), ay = fabsf(dy), az = fabsf(dz);
        const float ax2 = ax * ax, ay2 = ay * ay, az2 = az * az;
        ssum += ax2 * ax2 * ax + ay2 * ay2 * ay + az2 * az2 * az;
    }
    #pragma unroll
    for (int off = 32; off > 0; off >>= 1) ssum += __shfl_down(ssum, off, 64);
    const int wid = tid >> 6, lane = tid & 63;
    if (lane == 0) red[wid] = ssum;
    __syncthreads();
    if (tid == 0) {
        atomicAdd(&acc[b * 2 + dir], red[0] + red[1] + red[2] + red[3]);
        __threadfence();
        if (atomicAdd(fcnt, 1u) == 63u) {     // globally last tile: finalize
            float total = 0.0f;
            #pragma unroll
            for (int k = 0; k < 16; ++k) total += powf(atomicAdd(&acc[k], 0.0f), 0.2f);
            out[0] = total * 0.125f;
        }
    }
}

// ================= round-2 proven fallback =================
__global__ __launch_bounds__(BQ) void chamfer_nn_split_kernel(
    const float* __restrict__ x, const float* __restrict__ y,
    unsigned long long* __restrict__ packed, int N, int M)
{
    __shared__ float4 sref[1024];
    const int bid = blockIdx.x, split = bid & 3, qb = bid >> 2;
    const int tile = qb & 15, dir = (qb >> 4) & 1, b = qb >> 5;
    const float* Q; const float* R;
    if (dir == 0) { Q = x + (size_t)b * N * 3; R = y + (size_t)b * M * 3; }
    else          { Q = y + (size_t)b * M * 3; R = x + (size_t)b * N * 3; }
    const int tid = threadIdx.x, q = tile * BQ + tid, base = split * 1024;
    for (int j = tid; j < 1024; j += BQ) {
        const float rx = R[(size_t)(base + j) * 3 + 0];
        const float ry = R[(size_t)(base + j) * 3 + 1];
        const float rz = R[(size_t)(base + j) * 3 + 2];
        sref[j] = make_float4(rx, ry, rz, 0.5f * (rx * rx + ry * ry + rz * rz));
    }
    __syncthreads();
    const float qx = Q[q * 3 + 0], qy = Q[q * 3 + 1], qz = Q[q * 3 + 2];
    float best = 3.4e38f; int bestj = base;
    #pragma unroll 8
    for (int j = 0; j < 1024; ++j) {
        const float4 r = sref[j];
        float t = __fmaf_rn(-qx, r.x, r.w);
        t = __fmaf_rn(-qy, r.y, t);
        t = __fmaf_rn(-qz, r.z, t);
        const bool c = t < best;
        best = c ? t : best; bestj = c ? (base + j) : bestj;
    }
    const size_t idx = ((size_t)dir * 8 + b) * (size_t)N + q;
    atomicMin(&packed[idx], ((unsigned long long)float_ord(best) << 32) | (unsigned int)bestj);
}

__global__ __launch_bounds__(BQ) void chamfer_gather_kernel(
    const float* __restrict__ x, const float* __restrict__ y,
    const unsigned long long* __restrict__ packed,
    float* __restrict__ acc, int N, int M)
{
    __shared__ float red[4];
    const int tid = threadIdx.x;
    const size_t gq = (size_t)blockIdx.x * BQ + tid;
    const int dir = (int)(gq / ((size_t)8 * N));
    const size_t rem = gq - (size_t)dir * 8 * N;
    const int b = (int)(rem / N), q = (int)(rem - (size_t)b * N);
    const float* Q; const float* R;
    if (dir == 0) { Q = x + (size_t)b * N * 3; R = y + (size_t)b * M * 3; }
    else          { Q = y + (size_t)b * M * 3; R = x + (size_t)b * N * 3; }
    const int j = (int)(unsigned int)packed[gq];
    const float dx = Q[q * 3 + 0] - R[(size_t)j * 3 + 0];
    const float dy = Q[q * 3 + 1] - R[(size_t)j * 3 + 1];
    const float dz = Q[q * 3 + 2] - R[(size_t)j * 3 + 2];
    const float ax = fabsf(dx), ay = fabsf(dy), az = fabsf(dz);
    const float ax2 = ax * ax, ay2 = ay * ay, az2 = az * az;
    float s = ax2 * ax2 * ax + ay2 * ay2 * ay + az2 * az2 * az;
    #pragma unroll
    for (int off = 32; off > 0; off >>= 1) s += __shfl_down(s, off, 64);
    const int wid = tid >> 6, lane = tid & 63;
    if (lane == 0) red[wid] = s;
    __syncthreads();
    if (tid == 0) atomicAdd(&acc[b * 2 + dir], red[0] + red[1] + red[2] + red[3]);
}

__global__ void chamfer_finalize_kernel(const float* __restrict__ acc,
                                        float* __restrict__ out)
{
    if (threadIdx.x == 0 && blockIdx.x == 0) {
        float total = 0.0f;
        #pragma unroll
        for (int i = 0; i < 16; ++i) total += powf(acc[i], 0.2f);
        *out = total * 0.125f;
    }
}

extern "C" void kernel_launch(void* const* d_in, const int* in_sizes, int n_in,
                              void* d_out, int out_size, void* d_ws, size_t ws_size,
                              hipStream_t stream)
{
    const float* x = (const float*)d_in[0];
    const float* y = (const float*)d_in[1];
    float* out = (float*)d_out;
    const int N = in_sizes[0] / 24;  // B=8, C=3
    const int M = in_sizes[1] / 24;

    const size_t needed_r4 = WS_PART + (size_t)SPLITS * 65536 * 8;  // ~8.4 MB

    if (N == 4096 && M == 4096 && ws_size >= needed_r4) {
        unsigned char* ws = (unsigned char*)d_ws;
        hipMemsetAsync(ws, 0, 1024, stream);   // acc + tcnt + fcnt
        chamfer_r4<<<64 * SPLITS, BQ, 0, stream>>>(x, y, ws, out);
    } else {
        // round-2 proven path
        unsigned char* ws = (unsigned char*)d_ws;
        float* acc = (float*)ws;
        unsigned long long* ptab = (unsigned long long*)(ws + 4096);
        const size_t nQ = (size_t)2 * 8 * N;
        hipMemsetAsync(acc, 0, 64, stream);
        hipMemsetAsync(ptab, 0xFF, nQ * 8, stream);
        chamfer_nn_split_kernel<<<(int)(nQ / BQ) * 4, BQ, 0, stream>>>(x, y, ptab, N, M);
        chamfer_gather_kernel<<<(int)(nQ / BQ), BQ, 0, stream>>>(x, y, ptab, acc, N, M);
        chamfer_finalize_kernel<<<1, 64, 0, stream>>>(acc, out);
    }
}

// Round 5
// 100.860 us; speedup vs baseline: 1.5368x; 1.5368x over previous
//
#include <hip/hip_runtime.h>
#include <math.h>

// Chamfer p-norm loss (P=5), B=8, N=M=4096, C=3.
// R5: R4 post-mortem showed the in-kernel cross-block handshake (per-block
// __threadfence + agent-scope atomic loads) caused an 85% stall. Fix: back to
// fence-free multi-kernel structure (kernel boundary = visibility), keeping
// R4's verified math: pair-layout LDS refs, packed f32x2 FMA, group-id-only
// argmin tracking + exact-equality global re-scan, +64-folded positive scores.
// New: QPT=8 queries/thread with QUERY-pair packing (2 queries per f32x2) ->
// each pk_fma serves 2 (q,ref) pairs, each LDS byte serves 8 queries.
// LDS floor ~10 us/CU, VALU ~8 us/SIMD -> scan ~12-18 us.

#define BQ      256
#define QPT     8             // queries per thread
#define QP      (QPT / 2)     // query pairs per thread = 4
#define SPLITS  16
#define CH      256           // refs per split-block
#define GS      8             // refs per tracked group
#define NG      (CH / GS)     // 32 groups
#define BIGOFF  64.0f         // folds into h: scores stay > 0 (|q|^2/2 < 64)
#define NQTOT   65536         // 2 dirs * 8 batches * 4096 queries

typedef float f32x2 __attribute__((ext_vector_type(2)));

static __device__ __forceinline__ f32x2 mk2(float s) { f32x2 v; v.x = s; v.y = s; return v; }
static __device__ __forceinline__ f32x2 fma2(f32x2 a, f32x2 b, f32x2 c) {
    return __builtin_elementwise_fma(a, b, c);
}
static __device__ __forceinline__ f32x2 min2(f32x2 a, f32x2 b) {
    return __builtin_elementwise_min(a, b);
}
__device__ __forceinline__ unsigned int float_ord(float f) {
    unsigned int u = __float_as_uint(f);
    return (u & 0x80000000u) ? ~u : (u | 0x80000000u);
}

// ws layout: [0,64) acc[16] f32 | [4096, 4096+8MB) part u64[SPLITS][NQTOT]
#define WS_ACC  0
#define WS_PART 4096

// ---- scan: grid = 32 query-tiles (2048 q each) x 16 ref-splits = 512 blocks
__global__ __launch_bounds__(BQ) void chamfer_scan_r5(
    const float* __restrict__ x, const float* __restrict__ y,
    unsigned long long* __restrict__ part)
{
    __shared__ float4 sref[CH];  // pair layout: [2p]=(rx0,rx1,ry0,ry1) [2p+1]=(rz0,rz1,h0,h1)

    const int bid   = blockIdx.x;
    const int split = bid & (SPLITS - 1);
    const int tq    = bid >> 4;          // 0..31 = dir*16 + b*2 + t2
    const int dir   = tq >> 4;
    const int b     = (tq >> 1) & 7;
    const int t2    = tq & 1;

    const float* Q; const float* R;
    if (dir == 0) { Q = x + (size_t)b * 4096 * 3; R = y + (size_t)b * 4096 * 3; }
    else          { Q = y + (size_t)b * 4096 * 3; R = x + (size_t)b * 4096 * 3; }

    const int tid = threadIdx.x;

    // stage CH refs (pair layout, h = |r|^2/2 + 64 folded in)
    if (tid < CH / 2) {
        const float* rp = R + (size_t)(split * CH + 2 * tid) * 3;
        const float f0 = rp[0], f1 = rp[1], f2 = rp[2];
        const float f3 = rp[3], f4 = rp[4], f5 = rp[5];
        const float h0 = fmaf(0.5f * f0, f0, fmaf(0.5f * f1, f1, fmaf(0.5f * f2, f2, BIGOFF)));
        const float h1 = fmaf(0.5f * f3, f3, fmaf(0.5f * f4, f4, fmaf(0.5f * f5, f5, BIGOFF)));
        sref[2 * tid]     = make_float4(f0, f3, f1, f4);
        sref[2 * tid + 1] = make_float4(f2, f5, h0, h1);
    }

    // 8 queries/thread packed as 4 query-pairs: pair p = queries (2p, 2p+1)
    f32x2 nqx[QP], nqy[QP], nqz[QP];
    #pragma unroll
    for (int p = 0; p < QP; ++p) {
        const int ql0 = t2 * 2048 + (2 * p) * 256 + tid;
        const int ql1 = ql0 + 256;
        nqx[p].x = -Q[ql0 * 3 + 0]; nqx[p].y = -Q[ql1 * 3 + 0];
        nqy[p].x = -Q[ql0 * 3 + 1]; nqy[p].y = -Q[ql1 * 3 + 1];
        nqz[p].x = -Q[ql0 * 3 + 2]; nqz[p].y = -Q[ql1 * 3 + 2];
    }
    __syncthreads();

    f32x2 best2[QP]; int bgA[QP], bgB[QP];
    #pragma unroll
    for (int p = 0; p < QP; ++p) { best2[p] = mk2(3.4e38f); bgA[p] = 0; bgB[p] = 0; }

    #pragma unroll 2
    for (int g = 0; g < NG; ++g) {
        f32x2 macc[QP];
        #pragma unroll
        for (int p = 0; p < QP; ++p) macc[p] = mk2(3.4e38f);
        #pragma unroll
        for (int k = 0; k < GS / 2; ++k) {        // 4 ref-pairs per group
            const float4 a = sref[(g * 4 + k) * 2];
            const float4 c = sref[(g * 4 + k) * 2 + 1];
            const f32x2 rxl = mk2(a.x), rxh = mk2(a.y);
            const f32x2 ryl = mk2(a.z), ryh = mk2(a.w);
            const f32x2 rzl = mk2(c.x), rzh = mk2(c.y);
            const f32x2 hl  = mk2(c.z), hh2 = mk2(c.w);
            #pragma unroll
            for (int p = 0; p < QP; ++p) {
                const f32x2 tA = fma2(nqx[p], rxl, fma2(nqy[p], ryl, fma2(nqz[p], rzl, hl)));
                const f32x2 tB = fma2(nqx[p], rxh, fma2(nqy[p], ryh, fma2(nqz[p], rzh, hh2)));
                macc[p] = min2(macc[p], min2(tA, tB));
            }
        }
        #pragma unroll
        for (int p = 0; p < QP; ++p) {
            const bool cA = macc[p].x < best2[p].x;   // strict <: earliest group on ties
            best2[p].x = cA ? macc[p].x : best2[p].x;
            bgA[p]     = cA ? g : bgA[p];
            const bool cB = macc[p].y < best2[p].y;
            best2[p].y = cB ? macc[p].y : best2[p].y;
            bgB[p]     = cB ? g : bgB[p];
        }
    }

    // exact index: re-scan winning GS-ref group from global R (L1-resident);
    // bit-identical fma/h chain reproduces the packed-path score exactly.
    #pragma unroll
    for (int p = 0; p < QP; ++p) {
        #pragma unroll
        for (int hh = 0; hh < 2; ++hh) {
            const float bscore = hh ? best2[p].y : best2[p].x;
            const int   bg     = hh ? bgB[p]     : bgA[p];
            const float qx = hh ? -nqx[p].y : -nqx[p].x;
            const float qy = hh ? -nqy[p].y : -nqy[p].x;
            const float qz = hh ? -nqz[p].y : -nqz[p].x;
            const int basej = split * CH + bg * GS;
            int bj = basej;
            #pragma unroll
            for (int j = GS - 1; j >= 0; --j) {      // descending: smallest j wins
                const float* rp = R + (size_t)(basej + j) * 3;
                const float rx = rp[0], ry = rp[1], rz = rp[2];
                const float h = fmaf(0.5f * rx, rx, fmaf(0.5f * ry, ry, fmaf(0.5f * rz, rz, BIGOFF)));
                const float s = fmaf(-qx, rx, fmaf(-qy, ry, fmaf(-qz, rz, h)));
                if (s == bscore) bj = basej + j;
            }
            const size_t qidx = (size_t)tq * 2048 + (2 * p + hh) * 256 + tid;
            part[(size_t)split * NQTOT + qidx] =
                ((unsigned long long)__float_as_uint(bscore) << 32) | (unsigned int)bj;
        }
    }
}

// ---- combine + gather (kernel boundary provides cross-XCD visibility)
__global__ __launch_bounds__(BQ) void chamfer_gather_r5(
    const float* __restrict__ x, const float* __restrict__ y,
    const unsigned long long* __restrict__ part, float* __restrict__ acc)
{
    __shared__ float red[4];
    const int tid = threadIdx.x;
    const int gq  = blockIdx.x * BQ + tid;   // 0..65535 = dir*32768 + b*4096 + q
    const int dir = gq >> 15;
    const int rem = gq & 32767;
    const int b   = rem >> 12;
    const int q   = rem & 4095;

    const float* Q; const float* R;
    if (dir == 0) { Q = x + (size_t)b * 4096 * 3; R = y + (size_t)b * 4096 * 3; }
    else          { Q = y + (size_t)b * 4096 * 3; R = x + (size_t)b * 4096 * 3; }

    unsigned long long w = ~0ull;            // positive scores: u64 order == (score, j)
    #pragma unroll 4
    for (int s = 0; s < SPLITS; ++s) {
        const unsigned long long v = part[(size_t)s * NQTOT + gq];  // coalesced
        w = (v < w) ? v : w;
    }
    const int j = (int)(unsigned int)w;
    const float dx = Q[q * 3 + 0] - R[(size_t)j * 3 + 0];
    const float dy = Q[q * 3 + 1] - R[(size_t)j * 3 + 1];
    const float dz = Q[q * 3 + 2] - R[(size_t)j * 3 + 2];
    const float ax = fabsf(dx), ay = fabsf(dy), az = fabsf(dz);
    const float ax2 = ax * ax, ay2 = ay * ay, az2 = az * az;
    float s = ax2 * ax2 * ax + ay2 * ay2 * ay + az2 * az2 * az;

    #pragma unroll
    for (int off = 32; off > 0; off >>= 1) s += __shfl_down(s, off, 64);
    const int wid = tid >> 6, lane = tid & 63;
    if (lane == 0) red[wid] = s;
    __syncthreads();
    if (tid == 0) atomicAdd(&acc[b * 2 + dir], red[0] + red[1] + red[2] + red[3]);
}

__global__ void chamfer_finalize_kernel(const float* __restrict__ acc,
                                        float* __restrict__ out)
{
    if (threadIdx.x == 0 && blockIdx.x == 0) {
        float total = 0.0f;
        #pragma unroll
        for (int i = 0; i < 16; ++i) total += powf(acc[i], 0.2f);
        *out = total * 0.125f;
    }
}

// ================= round-2 proven fallback =================
__global__ __launch_bounds__(BQ) void chamfer_nn_split_kernel(
    const float* __restrict__ x, const float* __restrict__ y,
    unsigned long long* __restrict__ packed, int N, int M)
{
    __shared__ float4 sref[1024];
    const int bid = blockIdx.x, split = bid & 3, qb = bid >> 2;
    const int tile = qb & 15, dir = (qb >> 4) & 1, b = qb >> 5;
    const float* Q; const float* R;
    if (dir == 0) { Q = x + (size_t)b * N * 3; R = y + (size_t)b * M * 3; }
    else          { Q = y + (size_t)b * M * 3; R = x + (size_t)b * N * 3; }
    const int tid = threadIdx.x, q = tile * BQ + tid, base = split * 1024;
    for (int j = tid; j < 1024; j += BQ) {
        const float rx = R[(size_t)(base + j) * 3 + 0];
        const float ry = R[(size_t)(base + j) * 3 + 1];
        const float rz = R[(size_t)(base + j) * 3 + 2];
        sref[j] = make_float4(rx, ry, rz, 0.5f * (rx * rx + ry * ry + rz * rz));
    }
    __syncthreads();
    const float qx = Q[q * 3 + 0], qy = Q[q * 3 + 1], qz = Q[q * 3 + 2];
    float best = 3.4e38f; int bestj = base;
    #pragma unroll 8
    for (int j = 0; j < 1024; ++j) {
        const float4 r = sref[j];
        float t = __fmaf_rn(-qx, r.x, r.w);
        t = __fmaf_rn(-qy, r.y, t);
        t = __fmaf_rn(-qz, r.z, t);
        const bool c = t < best;
        best = c ? t : best; bestj = c ? (base + j) : bestj;
    }
    const size_t idx = ((size_t)dir * 8 + b) * (size_t)N + q;
    atomicMin(&packed[idx], ((unsigned long long)float_ord(best) << 32) | (unsigned int)bestj);
}

__global__ __launch_bounds__(BQ) void chamfer_gather_kernel(
    const float* __restrict__ x, const float* __restrict__ y,
    const unsigned long long* __restrict__ packed,
    float* __restrict__ acc, int N, int M)
{
    __shared__ float red[4];
    const int tid = threadIdx.x;
    const size_t gq = (size_t)blockIdx.x * BQ + tid;
    const int dir = (int)(gq / ((size_t)8 * N));
    const size_t rem = gq - (size_t)dir * 8 * N;
    const int b = (int)(rem / N), q = (int)(rem - (size_t)b * N);
    const float* Q; const float* R;
    if (dir == 0) { Q = x + (size_t)b * N * 3; R = y + (size_t)b * M * 3; }
    else          { Q = y + (size_t)b * M * 3; R = x + (size_t)b * N * 3; }
    const int j = (int)(unsigned int)packed[gq];
    const float dx = Q[q * 3 + 0] - R[(size_t)j * 3 + 0];
    const float dy = Q[q * 3 + 1] - R[(size_t)j * 3 + 1];
    const float dz = Q[q * 3 + 2] - R[(size_t)j * 3 + 2];
    const float ax = fabsf(dx), ay = fabsf(dy), az = fabsf(dz);
    const float ax2 = ax * ax, ay2 = ay * ay, az2 = az * az;
    float s = ax2 * ax2 * ax + ay2 * ay2 * ay + az2 * az2 * az;
    #pragma unroll
    for (int off = 32; off > 0; off >>= 1) s += __shfl_down(s, off, 64);
    const int wid = tid >> 6, lane = tid & 63;
    if (lane == 0) red[wid] = s;
    __syncthreads();
    if (tid == 0) atomicAdd(&acc[b * 2 + dir], red[0] + red[1] + red[2] + red[3]);
}

extern "C" void kernel_launch(void* const* d_in, const int* in_sizes, int n_in,
                              void* d_out, int out_size, void* d_ws, size_t ws_size,
                              hipStream_t stream)
{
    const float* x = (const float*)d_in[0];
    const float* y = (const float*)d_in[1];
    float* out = (float*)d_out;
    const int N = in_sizes[0] / 24;  // B=8, C=3
    const int M = in_sizes[1] / 24;

    const size_t needed = WS_PART + (size_t)SPLITS * NQTOT * 8;  // ~8.4 MB

    if (N == 4096 && M == 4096 && ws_size >= needed) {
        unsigned char* ws = (unsigned char*)d_ws;
        float* acc = (float*)(ws + WS_ACC);
        unsigned long long* part = (unsigned long long*)(ws + WS_PART);
        hipMemsetAsync(acc, 0, 64, stream);
        chamfer_scan_r5<<<32 * SPLITS, BQ, 0, stream>>>(x, y, part);
        chamfer_gather_r5<<<NQTOT / BQ, BQ, 0, stream>>>(x, y, part, acc);
        chamfer_finalize_kernel<<<1, 64, 0, stream>>>(acc, out);
    } else {
        // round-2 proven path
        unsigned char* ws = (unsigned char*)d_ws;
        float* acc = (float*)ws;
        unsigned long long* ptab = (unsigned long long*)(ws + 4096);
        const size_t nQ = (size_t)2 * 8 * N;
        hipMemsetAsync(acc, 0, 64, stream);
        hipMemsetAsync(ptab, 0xFF, nQ * 8, stream);
        chamfer_nn_split_kernel<<<(int)(nQ / BQ) * 4, BQ, 0, stream>>>(x, y, ptab, N, M);
        chamfer_gather_kernel<<<(int)(nQ / BQ), BQ, 0, stream>>>(x, y, ptab, acc, N, M);
        chamfer_finalize_kernel<<<1, 64, 0, stream>>>(acc, out);
    }
}

// Round 6
// 95.714 us; speedup vs baseline: 1.6194x; 1.0538x over previous
//
#include <hip/hip_runtime.h>
#include <math.h>

// Chamfer p-norm loss (P=5), B=8, N=M=4096, C=3.
// R6: R5 profiling showed chamfer_finalize_kernel = 44 us with VALUBusy 0.008%
// (pure dispatch/serialization latency, constant across all rounds). Fix:
// eliminate the dispatch — fuse finalize into the gather kernel via the
// R3-proven counter handshake (threadfence + fcnt atomic; globally-last block
// reads acc agent-scope and writes the scalar), with 16-lane-parallel
// exp2f(0.2*log2f(v)) instead of serial powf. Scan kernel unchanged from R5
// (verified absmax 0.0): pair-layout LDS refs, packed f32x2 FMA, QPT=8 with
// query-pair packing, group-id argmin + exact-equality global re-scan,
// +64-folded positive scores so u64 order == (score, j) lexicographic order.

#define BQ      256
#define QPT     8             // queries per thread
#define QP      (QPT / 2)     // query pairs per thread = 4
#define SPLITS  16
#define CH      256           // refs per split-block
#define GS      8             // refs per tracked group
#define NG      (CH / GS)     // 32 groups
#define BIGOFF  64.0f         // folds into h: scores stay > 0 (|q|^2/2 < 64)
#define NQTOT   65536         // 2 dirs * 8 batches * 4096 queries

typedef float f32x2 __attribute__((ext_vector_type(2)));

static __device__ __forceinline__ f32x2 mk2(float s) { f32x2 v; v.x = s; v.y = s; return v; }
static __device__ __forceinline__ f32x2 fma2(f32x2 a, f32x2 b, f32x2 c) {
    return __builtin_elementwise_fma(a, b, c);
}
static __device__ __forceinline__ f32x2 min2(f32x2 a, f32x2 b) {
    return __builtin_elementwise_min(a, b);
}
__device__ __forceinline__ unsigned int float_ord(float f) {
    unsigned int u = __float_as_uint(f);
    return (u & 0x80000000u) ? ~u : (u | 0x80000000u);
}

// ws layout: [0,64) acc[16] f32 | [64,68) fcnt u32 | [4096,+8MB) part u64[SPLITS][NQTOT]
#define WS_ACC  0
#define WS_FCNT 64
#define WS_PART 4096

// ---- scan: grid = 32 query-tiles (2048 q each) x 16 ref-splits = 512 blocks
__global__ __launch_bounds__(BQ) void chamfer_scan_r5(
    const float* __restrict__ x, const float* __restrict__ y,
    unsigned long long* __restrict__ part)
{
    __shared__ float4 sref[CH];  // pair layout: [2p]=(rx0,rx1,ry0,ry1) [2p+1]=(rz0,rz1,h0,h1)

    const int bid   = blockIdx.x;
    const int split = bid & (SPLITS - 1);
    const int tq    = bid >> 4;          // 0..31 = dir*16 + b*2 + t2
    const int dir   = tq >> 4;
    const int b     = (tq >> 1) & 7;
    const int t2    = tq & 1;

    const float* Q; const float* R;
    if (dir == 0) { Q = x + (size_t)b * 4096 * 3; R = y + (size_t)b * 4096 * 3; }
    else          { Q = y + (size_t)b * 4096 * 3; R = x + (size_t)b * 4096 * 3; }

    const int tid = threadIdx.x;

    // stage CH refs (pair layout, h = |r|^2/2 + 64 folded in)
    if (tid < CH / 2) {
        const float* rp = R + (size_t)(split * CH + 2 * tid) * 3;
        const float f0 = rp[0], f1 = rp[1], f2 = rp[2];
        const float f3 = rp[3], f4 = rp[4], f5 = rp[5];
        const float h0 = fmaf(0.5f * f0, f0, fmaf(0.5f * f1, f1, fmaf(0.5f * f2, f2, BIGOFF)));
        const float h1 = fmaf(0.5f * f3, f3, fmaf(0.5f * f4, f4, fmaf(0.5f * f5, f5, BIGOFF)));
        sref[2 * tid]     = make_float4(f0, f3, f1, f4);
        sref[2 * tid + 1] = make_float4(f2, f5, h0, h1);
    }

    // 8 queries/thread packed as 4 query-pairs: pair p = queries (2p, 2p+1)
    f32x2 nqx[QP], nqy[QP], nqz[QP];
    #pragma unroll
    for (int p = 0; p < QP; ++p) {
        const int ql0 = t2 * 2048 + (2 * p) * 256 + tid;
        const int ql1 = ql0 + 256;
        nqx[p].x = -Q[ql0 * 3 + 0]; nqx[p].y = -Q[ql1 * 3 + 0];
        nqy[p].x = -Q[ql0 * 3 + 1]; nqy[p].y = -Q[ql1 * 3 + 1];
        nqz[p].x = -Q[ql0 * 3 + 2]; nqz[p].y = -Q[ql1 * 3 + 2];
    }
    __syncthreads();

    f32x2 best2[QP]; int bgA[QP], bgB[QP];
    #pragma unroll
    for (int p = 0; p < QP; ++p) { best2[p] = mk2(3.4e38f); bgA[p] = 0; bgB[p] = 0; }

    #pragma unroll 2
    for (int g = 0; g < NG; ++g) {
        f32x2 macc[QP];
        #pragma unroll
        for (int p = 0; p < QP; ++p) macc[p] = mk2(3.4e38f);
        #pragma unroll
        for (int k = 0; k < GS / 2; ++k) {        // 4 ref-pairs per group
            const float4 a = sref[(g * 4 + k) * 2];
            const float4 c = sref[(g * 4 + k) * 2 + 1];
            const f32x2 rxl = mk2(a.x), rxh = mk2(a.y);
            const f32x2 ryl = mk2(a.z), ryh = mk2(a.w);
            const f32x2 rzl = mk2(c.x), rzh = mk2(c.y);
            const f32x2 hl  = mk2(c.z), hh2 = mk2(c.w);
            #pragma unroll
            for (int p = 0; p < QP; ++p) {
                const f32x2 tA = fma2(nqx[p], rxl, fma2(nqy[p], ryl, fma2(nqz[p], rzl, hl)));
                const f32x2 tB = fma2(nqx[p], rxh, fma2(nqy[p], ryh, fma2(nqz[p], rzh, hh2)));
                macc[p] = min2(macc[p], min2(tA, tB));
            }
        }
        #pragma unroll
        for (int p = 0; p < QP; ++p) {
            const bool cA = macc[p].x < best2[p].x;   // strict <: earliest group on ties
            best2[p].x = cA ? macc[p].x : best2[p].x;
            bgA[p]     = cA ? g : bgA[p];
            const bool cB = macc[p].y < best2[p].y;
            best2[p].y = cB ? macc[p].y : best2[p].y;
            bgB[p]     = cB ? g : bgB[p];
        }
    }

    // exact index: re-scan winning GS-ref group from global R (L1-resident);
    // bit-identical fma/h chain reproduces the packed-path score exactly.
    #pragma unroll
    for (int p = 0; p < QP; ++p) {
        #pragma unroll
        for (int hh = 0; hh < 2; ++hh) {
            const float bscore = hh ? best2[p].y : best2[p].x;
            const int   bg     = hh ? bgB[p]     : bgA[p];
            const float qx = hh ? -nqx[p].y : -nqx[p].x;
            const float qy = hh ? -nqy[p].y : -nqy[p].x;
            const float qz = hh ? -nqz[p].y : -nqz[p].x;
            const int basej = split * CH + bg * GS;
            int bj = basej;
            #pragma unroll
            for (int j = GS - 1; j >= 0; --j) {      // descending: smallest j wins
                const float* rp = R + (size_t)(basej + j) * 3;
                const float rx = rp[0], ry = rp[1], rz = rp[2];
                const float h = fmaf(0.5f * rx, rx, fmaf(0.5f * ry, ry, fmaf(0.5f * rz, rz, BIGOFF)));
                const float s = fmaf(-qx, rx, fmaf(-qy, ry, fmaf(-qz, rz, h)));
                if (s == bscore) bj = basej + j;
            }
            const size_t qidx = (size_t)tq * 2048 + (2 * p + hh) * 256 + tid;
            part[(size_t)split * NQTOT + qidx] =
                ((unsigned long long)__float_as_uint(bscore) << 32) | (unsigned int)bj;
        }
    }
}

// ---- combine + gather + FUSED finalize (kernel boundary gives scan->gather
//      visibility; counter handshake gives gather->finalize visibility)
__global__ __launch_bounds__(BQ) void chamfer_gather_fin_r6(
    const float* __restrict__ x, const float* __restrict__ y,
    const unsigned long long* __restrict__ part,
    float* __restrict__ acc, unsigned int* __restrict__ fcnt,
    float* __restrict__ out)
{
    __shared__ float red[4];
    __shared__ int s_done;

    const int tid = threadIdx.x;
    const int gq  = blockIdx.x * BQ + tid;   // 0..65535 = dir*32768 + b*4096 + q
    const int dir = gq >> 15;
    const int rem = gq & 32767;
    const int b   = rem >> 12;
    const int q   = rem & 4095;

    const float* Q; const float* R;
    if (dir == 0) { Q = x + (size_t)b * 4096 * 3; R = y + (size_t)b * 4096 * 3; }
    else          { Q = y + (size_t)b * 4096 * 3; R = x + (size_t)b * 4096 * 3; }

    unsigned long long w = ~0ull;            // positive scores: u64 order == (score, j)
    #pragma unroll 4
    for (int s = 0; s < SPLITS; ++s) {
        const unsigned long long v = part[(size_t)s * NQTOT + gq];  // coalesced
        w = (v < w) ? v : w;
    }
    const int j = (int)(unsigned int)w;
    const float dx = Q[q * 3 + 0] - R[(size_t)j * 3 + 0];
    const float dy = Q[q * 3 + 1] - R[(size_t)j * 3 + 1];
    const float dz = Q[q * 3 + 2] - R[(size_t)j * 3 + 2];
    const float ax = fabsf(dx), ay = fabsf(dy), az = fabsf(dz);
    const float ax2 = ax * ax, ay2 = ay * ay, az2 = az * az;
    float s = ax2 * ax2 * ax + ay2 * ay2 * ay + az2 * az2 * az;

    #pragma unroll
    for (int off = 32; off > 0; off >>= 1) s += __shfl_down(s, off, 64);
    const int wid = tid >> 6, lane = tid & 63;
    if (lane == 0) red[wid] = s;
    __syncthreads();

    if (tid == 0) {
        atomicAdd(&acc[b * 2 + dir], red[0] + red[1] + red[2] + red[3]);
        __threadfence();                          // release acc before counter
        const unsigned int done = atomicAdd(fcnt, 1u);
        s_done = (done == gridDim.x - 1);
    }
    __syncthreads();
    if (!s_done) return;

    // globally-last block: finalize. 16-lane-parallel x^0.2 via exp2/log2
    // (v_log_f32 + v_mul + v_exp_f32; rel err ~1e-5 << 6.9e-2 threshold).
    __threadfence();                              // acquire side
    if (tid < 64) {
        float v = 0.0f;
        if (tid < 16) {
            const float a = __hip_atomic_load(&acc[tid], __ATOMIC_RELAXED,
                                              __HIP_MEMORY_SCOPE_AGENT);
            v = exp2f(0.2f * log2f(a));
        }
        #pragma unroll
        for (int off = 8; off > 0; off >>= 1) v += __shfl_down(v, off, 64);
        if (tid == 0) out[0] = v * 0.125f;        // mean over B=8
    }
}

// ================= round-2 proven fallback =================
__global__ __launch_bounds__(BQ) void chamfer_nn_split_kernel(
    const float* __restrict__ x, const float* __restrict__ y,
    unsigned long long* __restrict__ packed, int N, int M)
{
    __shared__ float4 sref[1024];
    const int bid = blockIdx.x, split = bid & 3, qb = bid >> 2;
    const int tile = qb & 15, dir = (qb >> 4) & 1, b = qb >> 5;
    const float* Q; const float* R;
    if (dir == 0) { Q = x + (size_t)b * N * 3; R = y + (size_t)b * M * 3; }
    else          { Q = y + (size_t)b * M * 3; R = x + (size_t)b * N * 3; }
    const int tid = threadIdx.x, q = tile * BQ + tid, base = split * 1024;
    for (int j = tid; j < 1024; j += BQ) {
        const float rx = R[(size_t)(base + j) * 3 + 0];
        const float ry = R[(size_t)(base + j) * 3 + 1];
        const float rz = R[(size_t)(base + j) * 3 + 2];
        sref[j] = make_float4(rx, ry, rz, 0.5f * (rx * rx + ry * ry + rz * rz));
    }
    __syncthreads();
    const float qx = Q[q * 3 + 0], qy = Q[q * 3 + 1], qz = Q[q * 3 + 2];
    float best = 3.4e38f; int bestj = base;
    #pragma unroll 8
    for (int j = 0; j < 1024; ++j) {
        const float4 r = sref[j];
        float t = __fmaf_rn(-qx, r.x, r.w);
        t = __fmaf_rn(-qy, r.y, t);
        t = __fmaf_rn(-qz, r.z, t);
        const bool c = t < best;
        best = c ? t : best; bestj = c ? (base + j) : bestj;
    }
    const size_t idx = ((size_t)dir * 8 + b) * (size_t)N + q;
    atomicMin(&packed[idx], ((unsigned long long)float_ord(best) << 32) | (unsigned int)bestj);
}

__global__ __launch_bounds__(BQ) void chamfer_gather_kernel(
    const float* __restrict__ x, const float* __restrict__ y,
    const unsigned long long* __restrict__ packed,
    float* __restrict__ acc, int N, int M)
{
    __shared__ float red[4];
    const int tid = threadIdx.x;
    const size_t gq = (size_t)blockIdx.x * BQ + tid;
    const int dir = (int)(gq / ((size_t)8 * N));
    const size_t rem = gq - (size_t)dir * 8 * N;
    const int b = (int)(rem / N), q = (int)(rem - (size_t)b * N);
    const float* Q; const float* R;
    if (dir == 0) { Q = x + (size_t)b * N * 3; R = y + (size_t)b * M * 3; }
    else          { Q = y + (size_t)b * M * 3; R = x + (size_t)b * N * 3; }
    const int j = (int)(unsigned int)packed[gq];
    const float dx = Q[q * 3 + 0] - R[(size_t)j * 3 + 0];
    const float dy = Q[q * 3 + 1] - R[(size_t)j * 3 + 1];
    const float dz = Q[q * 3 + 2] - R[(size_t)j * 3 + 2];
    const float ax = fabsf(dx), ay = fabsf(dy), az = fabsf(dz);
    const float ax2 = ax * ax, ay2 = ay * ay, az2 = az * az;
    float s = ax2 * ax2 * ax + ay2 * ay2 * ay + az2 * az2 * az;
    #pragma unroll
    for (int off = 32; off > 0; off >>= 1) s += __shfl_down(s, off, 64);
    const int wid = tid >> 6, lane = tid & 63;
    if (lane == 0) red[wid] = s;
    __syncthreads();
    if (tid == 0) atomicAdd(&acc[b * 2 + dir], red[0] + red[1] + red[2] + red[3]);
}

__global__ void chamfer_finalize_kernel(const float* __restrict__ acc,
                                        float* __restrict__ out)
{
    if (threadIdx.x == 0 && blockIdx.x == 0) {
        float total = 0.0f;
        #pragma unroll
        for (int i = 0; i < 16; ++i) total += powf(acc[i], 0.2f);
        *out = total * 0.125f;
    }
}

extern "C" void kernel_launch(void* const* d_in, const int* in_sizes, int n_in,
                              void* d_out, int out_size, void* d_ws, size_t ws_size,
                              hipStream_t stream)
{
    const float* x = (const float*)d_in[0];
    const float* y = (const float*)d_in[1];
    float* out = (float*)d_out;
    const int N = in_sizes[0] / 24;  // B=8, C=3
    const int M = in_sizes[1] / 24;

    const size_t needed = WS_PART + (size_t)SPLITS * NQTOT * 8;  // ~8.4 MB

    if (N == 4096 && M == 4096 && ws_size >= needed) {
        unsigned char* ws = (unsigned char*)d_ws;
        float* acc = (float*)(ws + WS_ACC);
        unsigned int* fcnt = (unsigned int*)(ws + WS_FCNT);
        unsigned long long* part = (unsigned long long*)(ws + WS_PART);
        hipMemsetAsync(ws, 0, 128, stream);   // acc + fcnt
        chamfer_scan_r5<<<32 * SPLITS, BQ, 0, stream>>>(x, y, part);
        chamfer_gather_fin_r6<<<NQTOT / BQ, BQ, 0, stream>>>(x, y, part, acc, fcnt, out);
    } else {
        // round-2 proven path
        unsigned char* ws = (unsigned char*)d_ws;
        float* acc = (float*)ws;
        unsigned long long* ptab = (unsigned long long*)(ws + 4096);
        const size_t nQ = (size_t)2 * 8 * N;
        hipMemsetAsync(acc, 0, 64, stream);
        hipMemsetAsync(ptab, 0xFF, nQ * 8, stream);
        chamfer_nn_split_kernel<<<(int)(nQ / BQ) * 4, BQ, 0, stream>>>(x, y, ptab, N, M);
        chamfer_gather_kernel<<<(int)(nQ / BQ), BQ, 0, stream>>>(x, y, ptab, acc, N, M);
        chamfer_finalize_kernel<<<1, 64, 0, stream>>>(acc, out);
    }
}

// Round 7
// 93.206 us; speedup vs baseline: 1.6629x; 1.0269x over previous
//
#include <hip/hip_runtime.h>
#include <math.h>

// Chamfer p-norm loss (P=5), B=8, N=M=4096, C=3.
// R7: R6 revealed (a) the harness's 268MB d_ws poison = 41.5us unavoidable
// floor in the timed loop; (b) rocprof per-dispatch durs for tiny kernels are
// profiler-inflated (removing the "44us" finalize bought only 5us). True
// controllable budget ~52us (scan+gather+memset+gaps). Changes:
//  1. scan QPT 8->4 => 1024 blocks, 4 waves/SIMD (was 2): same ~2.3 VALU
//     inst/pair, but real latency hiding. Predicted scan ~13us.
//  2. memset dispatch eliminated: scan block 0 zeroes acc/fcnt (kernel
//     boundary = visibility). 2 dispatches total.
//  3. gather + fused finalize unchanged from R6 (verified absmax 0.0).

#define BQ      256
#define QPT     4             // queries per thread
#define QP      (QPT / 2)     // query pairs per thread = 2
#define SPLITS  16
#define CH      256           // refs per split-block
#define GS      8             // refs per tracked group
#define NG      (CH / GS)     // 32 groups
#define BIGOFF  64.0f         // folds into h: scores stay > 0 (|q|^2/2 < 64)
#define NQTOT   65536         // 2 dirs * 8 batches * 4096 queries
#define NTILE   64            // query tiles of 1024

typedef float f32x2 __attribute__((ext_vector_type(2)));

static __device__ __forceinline__ f32x2 mk2(float s) { f32x2 v; v.x = s; v.y = s; return v; }
static __device__ __forceinline__ f32x2 fma2(f32x2 a, f32x2 b, f32x2 c) {
    return __builtin_elementwise_fma(a, b, c);
}
static __device__ __forceinline__ f32x2 min2(f32x2 a, f32x2 b) {
    return __builtin_elementwise_min(a, b);
}
__device__ __forceinline__ unsigned int float_ord(float f) {
    unsigned int u = __float_as_uint(f);
    return (u & 0x80000000u) ? ~u : (u | 0x80000000u);
}

// ws layout: [0,64) acc[16] f32 | [64,68) fcnt u32 | [4096,+8MB) part u64[SPLITS][NQTOT]
#define WS_ACC  0
#define WS_FCNT 64
#define WS_PART 4096

// ---- scan: grid = 64 query-tiles (1024 q each) x 16 ref-splits = 1024 blocks
__global__ __launch_bounds__(BQ) void chamfer_scan_r7(
    const float* __restrict__ x, const float* __restrict__ y,
    unsigned long long* __restrict__ part, float* __restrict__ acc,
    unsigned int* __restrict__ fcnt)
{
    __shared__ float4 sref[CH];  // pair layout: [2p]=(rx0,rx1,ry0,ry1) [2p+1]=(rz0,rz1,h0,h1)

    const int bid   = blockIdx.x;
    const int split = bid & (SPLITS - 1);
    const int tq    = bid >> 4;          // 0..63 = dir*32 + b*4 + t4
    const int dir   = tq >> 5;
    const int b     = (tq >> 2) & 7;
    const int t4    = tq & 3;

    // zero acc + fcnt for the gather kernel (kernel boundary = visibility;
    // d_ws is re-poisoned to 0xAA before every timed launch)
    if (bid == 0 && threadIdx.x < 32) {
        if (threadIdx.x < 16) acc[threadIdx.x] = 0.0f;
        if (threadIdx.x == 16) *fcnt = 0u;
    }

    const float* Q; const float* R;
    if (dir == 0) { Q = x + (size_t)b * 4096 * 3; R = y + (size_t)b * 4096 * 3; }
    else          { Q = y + (size_t)b * 4096 * 3; R = x + (size_t)b * 4096 * 3; }

    const int tid = threadIdx.x;

    // stage CH refs (pair layout, h = |r|^2/2 + 64 folded in)
    if (tid < CH / 2) {
        const float* rp = R + (size_t)(split * CH + 2 * tid) * 3;
        const float f0 = rp[0], f1 = rp[1], f2 = rp[2];
        const float f3 = rp[3], f4 = rp[4], f5 = rp[5];
        const float h0 = fmaf(0.5f * f0, f0, fmaf(0.5f * f1, f1, fmaf(0.5f * f2, f2, BIGOFF)));
        const float h1 = fmaf(0.5f * f3, f3, fmaf(0.5f * f4, f4, fmaf(0.5f * f5, f5, BIGOFF)));
        sref[2 * tid]     = make_float4(f0, f3, f1, f4);
        sref[2 * tid + 1] = make_float4(f2, f5, h0, h1);
    }

    // 4 queries/thread packed as 2 query-pairs: pair p = queries (2p, 2p+1)
    f32x2 nqx[QP], nqy[QP], nqz[QP];
    #pragma unroll
    for (int p = 0; p < QP; ++p) {
        const int ql0 = t4 * 1024 + (2 * p) * 256 + tid;
        const int ql1 = ql0 + 256;
        nqx[p].x = -Q[ql0 * 3 + 0]; nqx[p].y = -Q[ql1 * 3 + 0];
        nqy[p].x = -Q[ql0 * 3 + 1]; nqy[p].y = -Q[ql1 * 3 + 1];
        nqz[p].x = -Q[ql0 * 3 + 2]; nqz[p].y = -Q[ql1 * 3 + 2];
    }
    __syncthreads();

    f32x2 best2[QP]; int bgA[QP], bgB[QP];
    #pragma unroll
    for (int p = 0; p < QP; ++p) { best2[p] = mk2(3.4e38f); bgA[p] = 0; bgB[p] = 0; }

    #pragma unroll 2
    for (int g = 0; g < NG; ++g) {
        f32x2 macc[QP];
        #pragma unroll
        for (int p = 0; p < QP; ++p) macc[p] = mk2(3.4e38f);
        #pragma unroll
        for (int k = 0; k < GS / 2; ++k) {        // 4 ref-pairs per group
            const float4 a = sref[(g * 4 + k) * 2];
            const float4 c = sref[(g * 4 + k) * 2 + 1];
            const f32x2 rxl = mk2(a.x), rxh = mk2(a.y);
            const f32x2 ryl = mk2(a.z), ryh = mk2(a.w);
            const f32x2 rzl = mk2(c.x), rzh = mk2(c.y);
            const f32x2 hl  = mk2(c.z), hh2 = mk2(c.w);
            #pragma unroll
            for (int p = 0; p < QP; ++p) {
                const f32x2 tA = fma2(nqx[p], rxl, fma2(nqy[p], ryl, fma2(nqz[p], rzl, hl)));
                const f32x2 tB = fma2(nqx[p], rxh, fma2(nqy[p], ryh, fma2(nqz[p], rzh, hh2)));
                macc[p] = min2(macc[p], min2(tA, tB));
            }
        }
        #pragma unroll
        for (int p = 0; p < QP; ++p) {
            const bool cA = macc[p].x < best2[p].x;   // strict <: earliest group on ties
            best2[p].x = cA ? macc[p].x : best2[p].x;
            bgA[p]     = cA ? g : bgA[p];
            const bool cB = macc[p].y < best2[p].y;
            best2[p].y = cB ? macc[p].y : best2[p].y;
            bgB[p]     = cB ? g : bgB[p];
        }
    }

    // exact index: re-scan winning GS-ref group from global R (L1-resident);
    // bit-identical fma/h chain reproduces the packed-path score exactly.
    #pragma unroll
    for (int p = 0; p < QP; ++p) {
        #pragma unroll
        for (int hh = 0; hh < 2; ++hh) {
            const float bscore = hh ? best2[p].y : best2[p].x;
            const int   bg     = hh ? bgB[p]     : bgA[p];
            const float qx = hh ? -nqx[p].y : -nqx[p].x;
            const float qy = hh ? -nqy[p].y : -nqy[p].x;
            const float qz = hh ? -nqz[p].y : -nqz[p].x;
            const int basej = split * CH + bg * GS;
            int bj = basej;
            #pragma unroll
            for (int j = GS - 1; j >= 0; --j) {      // descending: smallest j wins
                const float* rp = R + (size_t)(basej + j) * 3;
                const float rx = rp[0], ry = rp[1], rz = rp[2];
                const float h = fmaf(0.5f * rx, rx, fmaf(0.5f * ry, ry, fmaf(0.5f * rz, rz, BIGOFF)));
                const float s = fmaf(-qx, rx, fmaf(-qy, ry, fmaf(-qz, rz, h)));
                if (s == bscore) bj = basej + j;
            }
            const size_t qidx = (size_t)tq * 1024 + (2 * p + hh) * 256 + tid;
            part[(size_t)split * NQTOT + qidx] =
                ((unsigned long long)__float_as_uint(bscore) << 32) | (unsigned int)bj;
        }
    }
}

// ---- combine + gather + fused finalize (R6-verified)
__global__ __launch_bounds__(BQ) void chamfer_gather_fin_r6(
    const float* __restrict__ x, const float* __restrict__ y,
    const unsigned long long* __restrict__ part,
    float* __restrict__ acc, unsigned int* __restrict__ fcnt,
    float* __restrict__ out)
{
    __shared__ float red[4];
    __shared__ int s_done;

    const int tid = threadIdx.x;
    const int gq  = blockIdx.x * BQ + tid;   // 0..65535 = dir*32768 + b*4096 + q
    const int dir = gq >> 15;
    const int rem = gq & 32767;
    const int b   = rem >> 12;
    const int q   = rem & 4095;

    const float* Q; const float* R;
    if (dir == 0) { Q = x + (size_t)b * 4096 * 3; R = y + (size_t)b * 4096 * 3; }
    else          { Q = y + (size_t)b * 4096 * 3; R = x + (size_t)b * 4096 * 3; }

    unsigned long long w = ~0ull;            // positive scores: u64 order == (score, j)
    #pragma unroll
    for (int s = 0; s < SPLITS; ++s) {       // fully unrolled: 16 loads in flight
        const unsigned long long v = part[(size_t)s * NQTOT + gq];  // coalesced
        w = (v < w) ? v : w;
    }
    const int j = (int)(unsigned int)w;
    const float dx = Q[q * 3 + 0] - R[(size_t)j * 3 + 0];
    const float dy = Q[q * 3 + 1] - R[(size_t)j * 3 + 1];
    const float dz = Q[q * 3 + 2] - R[(size_t)j * 3 + 2];
    const float ax = fabsf(dx), ay = fabsf(dy), az = fabsf(dz);
    const float ax2 = ax * ax, ay2 = ay * ay, az2 = az * az;
    float s = ax2 * ax2 * ax + ay2 * ay2 * ay + az2 * az2 * az;

    #pragma unroll
    for (int off = 32; off > 0; off >>= 1) s += __shfl_down(s, off, 64);
    const int wid = tid >> 6, lane = tid & 63;
    if (lane == 0) red[wid] = s;
    __syncthreads();

    if (tid == 0) {
        atomicAdd(&acc[b * 2 + dir], red[0] + red[1] + red[2] + red[3]);
        __threadfence();                          // release acc before counter
        const unsigned int done = atomicAdd(fcnt, 1u);
        s_done = (done == gridDim.x - 1);
    }
    __syncthreads();
    if (!s_done) return;

    // globally-last block: finalize. x^0.2 via exp2/log2 (rel err ~1e-5).
    __threadfence();                              // acquire side
    if (tid < 64) {
        float v = 0.0f;
        if (tid < 16) {
            const float a = __hip_atomic_load(&acc[tid], __ATOMIC_RELAXED,
                                              __HIP_MEMORY_SCOPE_AGENT);
            v = exp2f(0.2f * log2f(a));
        }
        #pragma unroll
        for (int off = 8; off > 0; off >>= 1) v += __shfl_down(v, off, 64);
        if (tid == 0) out[0] = v * 0.125f;        // mean over B=8
    }
}

// ================= round-2 proven fallback =================
__global__ __launch_bounds__(BQ) void chamfer_nn_split_kernel(
    const float* __restrict__ x, const float* __restrict__ y,
    unsigned long long* __restrict__ packed, int N, int M)
{
    __shared__ float4 sref[1024];
    const int bid = blockIdx.x, split = bid & 3, qb = bid >> 2;
    const int tile = qb & 15, dir = (qb >> 4) & 1, b = qb >> 5;
    const float* Q; const float* R;
    if (dir == 0) { Q = x + (size_t)b * N * 3; R = y + (size_t)b * M * 3; }
    else          { Q = y + (size_t)b * M * 3; R = x + (size_t)b * N * 3; }
    const int tid = threadIdx.x, q = tile * BQ + tid, base = split * 1024;
    for (int j = tid; j < 1024; j += BQ) {
        const float rx = R[(size_t)(base + j) * 3 + 0];
        const float ry = R[(size_t)(base + j) * 3 + 1];
        const float rz = R[(size_t)(base + j) * 3 + 2];
        sref[j] = make_float4(rx, ry, rz, 0.5f * (rx * rx + ry * ry + rz * rz));
    }
    __syncthreads();
    const float qx = Q[q * 3 + 0], qy = Q[q * 3 + 1], qz = Q[q * 3 + 2];
    float best = 3.4e38f; int bestj = base;
    #pragma unroll 8
    for (int j = 0; j < 1024; ++j) {
        const float4 r = sref[j];
        float t = __fmaf_rn(-qx, r.x, r.w);
        t = __fmaf_rn(-qy, r.y, t);
        t = __fmaf_rn(-qz, r.z, t);
        const bool c = t < best;
        best = c ? t : best; bestj = c ? (base + j) : bestj;
    }
    const size_t idx = ((size_t)dir * 8 + b) * (size_t)N + q;
    atomicMin(&packed[idx], ((unsigned long long)float_ord(best) << 32) | (unsigned int)bestj);
}

__global__ __launch_bounds__(BQ) void chamfer_gather_kernel(
    const float* __restrict__ x, const float* __restrict__ y,
    const unsigned long long* __restrict__ packed,
    float* __restrict__ acc, int N, int M)
{
    __shared__ float red[4];
    const int tid = threadIdx.x;
    const size_t gq = (size_t)blockIdx.x * BQ + tid;
    const int dir = (int)(gq / ((size_t)8 * N));
    const size_t rem = gq - (size_t)dir * 8 * N;
    const int b = (int)(rem / N), q = (int)(rem - (size_t)b * N);
    const float* Q; const float* R;
    if (dir == 0) { Q = x + (size_t)b * N * 3; R = y + (size_t)b * M * 3; }
    else          { Q = y + (size_t)b * M * 3; R = x + (size_t)b * N * 3; }
    const int j = (int)(unsigned int)packed[gq];
    const float dx = Q[q * 3 + 0] - R[(size_t)j * 3 + 0];
    const float dy = Q[q * 3 + 1] - R[(size_t)j * 3 + 1];
    const float dz = Q[q * 3 + 2] - R[(size_t)j * 3 + 2];
    const float ax = fabsf(dx), ay = fabsf(dy), az = fabsf(dz);
    const float ax2 = ax * ax, ay2 = ay * ay, az2 = az * az;
    float s = ax2 * ax2 * ax + ay2 * ay2 * ay + az2 * az2 * az;
    #pragma unroll
    for (int off = 32; off > 0; off >>= 1) s += __shfl_down(s, off, 64);
    const int wid = tid >> 6, lane = tid & 63;
    if (lane == 0) red[wid] = s;
    __syncthreads();
    if (tid == 0) atomicAdd(&acc[b * 2 + dir], red[0] + red[1] + red[2] + red[3]);
}

__global__ void chamfer_finalize_kernel(const float* __restrict__ acc,
                                        float* __restrict__ out)
{
    if (threadIdx.x == 0 && blockIdx.x == 0) {
        float total = 0.0f;
        #pragma unroll
        for (int i = 0; i < 16; ++i) total += powf(acc[i], 0.2f);
        *out = total * 0.125f;
    }
}

extern "C" void kernel_launch(void* const* d_in, const int* in_sizes, int n_in,
                              void* d_out, int out_size, void* d_ws, size_t ws_size,
                              hipStream_t stream)
{
    const float* x = (const float*)d_in[0];
    const float* y = (const float*)d_in[1];
    float* out = (float*)d_out;
    const int N = in_sizes[0] / 24;  // B=8, C=3
    const int M = in_sizes[1] / 24;

    const size_t needed = WS_PART + (size_t)SPLITS * NQTOT * 8;  // ~8.4 MB

    if (N == 4096 && M == 4096 && ws_size >= needed) {
        unsigned char* ws = (unsigned char*)d_ws;
        float* acc = (float*)(ws + WS_ACC);
        unsigned int* fcnt = (unsigned int*)(ws + WS_FCNT);
        unsigned long long* part = (unsigned long long*)(ws + WS_PART);
        chamfer_scan_r7<<<NTILE * SPLITS, BQ, 0, stream>>>(x, y, part, acc, fcnt);
        chamfer_gather_fin_r6<<<NQTOT / BQ, BQ, 0, stream>>>(x, y, part, acc, fcnt, out);
    } else {
        // round-2 proven path
        unsigned char* ws = (unsigned char*)d_ws;
        float* acc = (float*)ws;
        unsigned long long* ptab = (unsigned long long*)(ws + 4096);
        const size_t nQ = (size_t)2 * 8 * N;
        hipMemsetAsync(acc, 0, 64, stream);
        hipMemsetAsync(ptab, 0xFF, nQ * 8, stream);
        chamfer_nn_split_kernel<<<(int)(nQ / BQ) * 4, BQ, 0, stream>>>(x, y, ptab, N, M);
        chamfer_gather_kernel<<<(int)(nQ / BQ), BQ, 0, stream>>>(x, y, ptab, acc, N, M);
        chamfer_finalize_kernel<<<1, 64, 0, stream>>>(acc, out);
    }
}

// Round 8
// 89.256 us; speedup vs baseline: 1.7365x; 1.0443x over previous
//
#include <hip/hip_runtime.h>
#include <math.h>

// Chamfer p-norm loss (P=5), B=8, N=M=4096, C=3.
// R8: trace shows the 268MB d_ws poison fill (~42us, 80% HBM peak) dominates;
// our kernels are <42us. Node-gap calibration: ~3-5us per graph node.
// Change: replace the 8MB per-split part table (scan writes 8MB, gather reads
// 16 u64/query) with a single 512KB atomicMax combine table on COMPLEMENTED
// keys: key = ~((score<<32)|j). Scores positive in (64,~200) => real keys in
// (0xBCB6.., 0xBD80..); both 0xAA poison and fresh zeros are below every real
// key, so NO init pass is needed (max(~packed) == min(packed), first-min
// tie-break preserved). Gather: 1 load/query. Scan math + gather/finalize
// handshake unchanged (absmax 0.0 verified since R5). Kernel boundary (not
// fences) for scan->gather visibility (R4 lesson).

#define BQ      256
#define QPT     4             // queries per thread
#define QP      (QPT / 2)     // query pairs per thread = 2
#define SPLITS  16
#define CH      256           // refs per split-block
#define GS      8             // refs per tracked group
#define NG      (CH / GS)     // 32 groups
#define BIGOFF  64.0f         // folds into h: scores stay in (64-|q|^2/2, ~200) > 0
#define NQTOT   65536         // 2 dirs * 8 batches * 4096 queries
#define NTILE   64            // query tiles of 1024

typedef float f32x2 __attribute__((ext_vector_type(2)));

static __device__ __forceinline__ f32x2 mk2(float s) { f32x2 v; v.x = s; v.y = s; return v; }
static __device__ __forceinline__ f32x2 fma2(f32x2 a, f32x2 b, f32x2 c) {
    return __builtin_elementwise_fma(a, b, c);
}
static __device__ __forceinline__ f32x2 min2(f32x2 a, f32x2 b) {
    return __builtin_elementwise_min(a, b);
}
__device__ __forceinline__ unsigned int float_ord(float f) {
    unsigned int u = __float_as_uint(f);
    return (u & 0x80000000u) ? ~u : (u | 0x80000000u);
}

// ws layout: [0,64) acc[16] f32 | [64,68) fcnt u32 | [4096, 4096+512K) tab u64[NQTOT]
#define WS_ACC  0
#define WS_FCNT 64
#define WS_TAB  4096

// ---- scan: grid = 64 query-tiles (1024 q each) x 16 ref-splits = 1024 blocks
__global__ __launch_bounds__(BQ) void chamfer_scan_r8(
    const float* __restrict__ x, const float* __restrict__ y,
    unsigned long long* __restrict__ tab, float* __restrict__ acc,
    unsigned int* __restrict__ fcnt)
{
    __shared__ float4 sref[CH];  // pair layout: [2p]=(rx0,rx1,ry0,ry1) [2p+1]=(rz0,rz1,h0,h1)

    const int bid   = blockIdx.x;
    const int split = bid & (SPLITS - 1);
    const int tq    = bid >> 4;          // 0..63 = dir*32 + b*4 + t4
    const int dir   = tq >> 5;
    const int b     = (tq >> 2) & 7;
    const int t4    = tq & 3;

    // zero acc + fcnt for the gather kernel (kernel boundary = visibility)
    if (bid == 0 && threadIdx.x < 32) {
        if (threadIdx.x < 16) acc[threadIdx.x] = 0.0f;
        if (threadIdx.x == 16) *fcnt = 0u;
    }

    const float* Q; const float* R;
    if (dir == 0) { Q = x + (size_t)b * 4096 * 3; R = y + (size_t)b * 4096 * 3; }
    else          { Q = y + (size_t)b * 4096 * 3; R = x + (size_t)b * 4096 * 3; }

    const int tid = threadIdx.x;

    // stage CH refs (pair layout, h = |r|^2/2 + 64 folded in)
    if (tid < CH / 2) {
        const float* rp = R + (size_t)(split * CH + 2 * tid) * 3;
        const float f0 = rp[0], f1 = rp[1], f2 = rp[2];
        const float f3 = rp[3], f4 = rp[4], f5 = rp[5];
        const float h0 = fmaf(0.5f * f0, f0, fmaf(0.5f * f1, f1, fmaf(0.5f * f2, f2, BIGOFF)));
        const float h1 = fmaf(0.5f * f3, f3, fmaf(0.5f * f4, f4, fmaf(0.5f * f5, f5, BIGOFF)));
        sref[2 * tid]     = make_float4(f0, f3, f1, f4);
        sref[2 * tid + 1] = make_float4(f2, f5, h0, h1);
    }

    // 4 queries/thread packed as 2 query-pairs: pair p = queries (2p, 2p+1)
    f32x2 nqx[QP], nqy[QP], nqz[QP];
    #pragma unroll
    for (int p = 0; p < QP; ++p) {
        const int ql0 = t4 * 1024 + (2 * p) * 256 + tid;
        const int ql1 = ql0 + 256;
        nqx[p].x = -Q[ql0 * 3 + 0]; nqx[p].y = -Q[ql1 * 3 + 0];
        nqy[p].x = -Q[ql0 * 3 + 1]; nqy[p].y = -Q[ql1 * 3 + 1];
        nqz[p].x = -Q[ql0 * 3 + 2]; nqz[p].y = -Q[ql1 * 3 + 2];
    }
    __syncthreads();

    f32x2 best2[QP]; int bgA[QP], bgB[QP];
    #pragma unroll
    for (int p = 0; p < QP; ++p) { best2[p] = mk2(3.4e38f); bgA[p] = 0; bgB[p] = 0; }

    #pragma unroll 2
    for (int g = 0; g < NG; ++g) {
        f32x2 macc[QP];
        #pragma unroll
        for (int p = 0; p < QP; ++p) macc[p] = mk2(3.4e38f);
        #pragma unroll
        for (int k = 0; k < GS / 2; ++k) {        // 4 ref-pairs per group
            const float4 a = sref[(g * 4 + k) * 2];
            const float4 c = sref[(g * 4 + k) * 2 + 1];
            const f32x2 rxl = mk2(a.x), rxh = mk2(a.y);
            const f32x2 ryl = mk2(a.z), ryh = mk2(a.w);
            const f32x2 rzl = mk2(c.x), rzh = mk2(c.y);
            const f32x2 hl  = mk2(c.z), hh2 = mk2(c.w);
            #pragma unroll
            for (int p = 0; p < QP; ++p) {
                const f32x2 tA = fma2(nqx[p], rxl, fma2(nqy[p], ryl, fma2(nqz[p], rzl, hl)));
                const f32x2 tB = fma2(nqx[p], rxh, fma2(nqy[p], ryh, fma2(nqz[p], rzh, hh2)));
                macc[p] = min2(macc[p], min2(tA, tB));
            }
        }
        #pragma unroll
        for (int p = 0; p < QP; ++p) {
            const bool cA = macc[p].x < best2[p].x;   // strict <: earliest group on ties
            best2[p].x = cA ? macc[p].x : best2[p].x;
            bgA[p]     = cA ? g : bgA[p];
            const bool cB = macc[p].y < best2[p].y;
            best2[p].y = cB ? macc[p].y : best2[p].y;
            bgB[p]     = cB ? g : bgB[p];
        }
    }

    // exact index: re-scan winning GS-ref group from global R (L1-resident);
    // bit-identical fma/h chain reproduces the packed-path score exactly.
    #pragma unroll
    for (int p = 0; p < QP; ++p) {
        #pragma unroll
        for (int hh = 0; hh < 2; ++hh) {
            const float bscore = hh ? best2[p].y : best2[p].x;
            const int   bg     = hh ? bgB[p]     : bgA[p];
            const float qx = hh ? -nqx[p].y : -nqx[p].x;
            const float qy = hh ? -nqy[p].y : -nqy[p].x;
            const float qz = hh ? -nqz[p].y : -nqz[p].x;
            const int basej = split * CH + bg * GS;
            int bj = basej;
            #pragma unroll
            for (int j = GS - 1; j >= 0; --j) {      // descending: smallest j wins
                const float* rp = R + (size_t)(basej + j) * 3;
                const float rx = rp[0], ry = rp[1], rz = rp[2];
                const float h = fmaf(0.5f * rx, rx, fmaf(0.5f * ry, ry, fmaf(0.5f * rz, rz, BIGOFF)));
                const float s = fmaf(-qx, rx, fmaf(-qy, ry, fmaf(-qz, rz, h)));
                if (s == bscore) bj = basej + j;
            }
            const size_t qidx = (size_t)tq * 1024 + (2 * p + hh) * 256 + tid;
            // complemented key: max(~packed) == min(packed); 0xAA poison and
            // fresh zeros are both < any real key -> no init required.
            const unsigned long long key =
                ~(((unsigned long long)__float_as_uint(bscore) << 32) | (unsigned int)bj);
            atomicMax(&tab[qidx], key);   // fire-and-forget (return unused)
        }
    }
}

// ---- gather + fused finalize: 1 table load per query
__global__ __launch_bounds__(BQ) void chamfer_gather_fin_r8(
    const float* __restrict__ x, const float* __restrict__ y,
    const unsigned long long* __restrict__ tab,
    float* __restrict__ acc, unsigned int* __restrict__ fcnt,
    float* __restrict__ out)
{
    __shared__ float red[4];
    __shared__ int s_done;

    const int tid = threadIdx.x;
    const int gq  = blockIdx.x * BQ + tid;   // 0..65535 = dir*32768 + b*4096 + q
    const int dir = gq >> 15;
    const int rem = gq & 32767;
    const int b   = rem >> 12;
    const int q   = rem & 4095;

    const float* Q; const float* R;
    if (dir == 0) { Q = x + (size_t)b * 4096 * 3; R = y + (size_t)b * 4096 * 3; }
    else          { Q = y + (size_t)b * 4096 * 3; R = x + (size_t)b * 4096 * 3; }

    const unsigned long long w = ~tab[gq];   // decode complemented key
    const int j = (int)(unsigned int)w;
    const float dx = Q[q * 3 + 0] - R[(size_t)j * 3 + 0];
    const float dy = Q[q * 3 + 1] - R[(size_t)j * 3 + 1];
    const float dz = Q[q * 3 + 2] - R[(size_t)j * 3 + 2];
    const float ax = fabsf(dx), ay = fabsf(dy), az = fabsf(dz);
    const float ax2 = ax * ax, ay2 = ay * ay, az2 = az * az;
    float s = ax2 * ax2 * ax + ay2 * ay2 * ay + az2 * az2 * az;

    #pragma unroll
    for (int off = 32; off > 0; off >>= 1) s += __shfl_down(s, off, 64);
    const int wid = tid >> 6, lane = tid & 63;
    if (lane == 0) red[wid] = s;
    __syncthreads();

    if (tid == 0) {
        atomicAdd(&acc[b * 2 + dir], red[0] + red[1] + red[2] + red[3]);
        __threadfence();                          // release acc before counter
        const unsigned int done = atomicAdd(fcnt, 1u);
        s_done = (done == gridDim.x - 1);
    }
    __syncthreads();
    if (!s_done) return;

    // globally-last block: finalize. x^0.2 via exp2/log2 (rel err ~1e-5).
    __threadfence();                              // acquire side
    if (tid < 64) {
        float v = 0.0f;
        if (tid < 16) {
            const float a = __hip_atomic_load(&acc[tid], __ATOMIC_RELAXED,
                                              __HIP_MEMORY_SCOPE_AGENT);
            v = exp2f(0.2f * log2f(a));
        }
        #pragma unroll
        for (int off = 8; off > 0; off >>= 1) v += __shfl_down(v, off, 64);
        if (tid == 0) out[0] = v * 0.125f;        // mean over B=8
    }
}

// ================= round-2 proven fallback (generic sizes) =================
__global__ __launch_bounds__(BQ) void chamfer_nn_split_kernel(
    const float* __restrict__ x, const float* __restrict__ y,
    unsigned long long* __restrict__ packed, int N, int M)
{
    __shared__ float4 sref[1024];
    const int bid = blockIdx.x, split = bid & 3, qb = bid >> 2;
    const int tile = qb & 15, dir = (qb >> 4) & 1, b = qb >> 5;
    const float* Q; const float* R;
    if (dir == 0) { Q = x + (size_t)b * N * 3; R = y + (size_t)b * M * 3; }
    else          { Q = y + (size_t)b * M * 3; R = x + (size_t)b * N * 3; }
    const int tid = threadIdx.x, q = tile * BQ + tid, base = split * 1024;
    for (int j = tid; j < 1024; j += BQ) {
        const float rx = R[(size_t)(base + j) * 3 + 0];
        const float ry = R[(size_t)(base + j) * 3 + 1];
        const float rz = R[(size_t)(base + j) * 3 + 2];
        sref[j] = make_float4(rx, ry, rz, 0.5f * (rx * rx + ry * ry + rz * rz));
    }
    __syncthreads();
    const float qx = Q[q * 3 + 0], qy = Q[q * 3 + 1], qz = Q[q * 3 + 2];
    float best = 3.4e38f; int bestj = base;
    #pragma unroll 8
    for (int j = 0; j < 1024; ++j) {
        const float4 r = sref[j];
        float t = __fmaf_rn(-qx, r.x, r.w);
        t = __fmaf_rn(-qy, r.y, t);
        t = __fmaf_rn(-qz, r.z, t);
        const bool c = t < best;
        best = c ? t : best; bestj = c ? (base + j) : bestj;
    }
    const size_t idx = ((size_t)dir * 8 + b) * (size_t)N + q;
    atomicMin(&packed[idx], ((unsigned long long)float_ord(best) << 32) | (unsigned int)bestj);
}

__global__ __launch_bounds__(BQ) void chamfer_gather_kernel(
    const float* __restrict__ x, const float* __restrict__ y,
    const unsigned long long* __restrict__ packed,
    float* __restrict__ acc, int N, int M)
{
    __shared__ float red[4];
    const int tid = threadIdx.x;
    const size_t gq = (size_t)blockIdx.x * BQ + tid;
    const int dir = (int)(gq / ((size_t)8 * N));
    const size_t rem = gq - (size_t)dir * 8 * N;
    const int b = (int)(rem / N), q = (int)(rem - (size_t)b * N);
    const float* Q; const float* R;
    if (dir == 0) { Q = x + (size_t)b * N * 3; R = y + (size_t)b * M * 3; }
    else          { Q = y + (size_t)b * M * 3; R = x + (size_t)b * N * 3; }
    const int j = (int)(unsigned int)packed[gq];
    const float dx = Q[q * 3 + 0] - R[(size_t)j * 3 + 0];
    const float dy = Q[q * 3 + 1] - R[(size_t)j * 3 + 1];
    const float dz = Q[q * 3 + 2] - R[(size_t)j * 3 + 2];
    const float ax = fabsf(dx), ay = fabsf(dy), az = fabsf(dz);
    const float ax2 = ax * ax, ay2 = ay * ay, az2 = az * az;
    float s = ax2 * ax2 * ax + ay2 * ay2 * ay + az2 * az2 * az;
    #pragma unroll
    for (int off = 32; off > 0; off >>= 1) s += __shfl_down(s, off, 64);
    const int wid = tid >> 6, lane = tid & 63;
    if (lane == 0) red[wid] = s;
    __syncthreads();
    if (tid == 0) atomicAdd(&acc[b * 2 + dir], red[0] + red[1] + red[2] + red[3]);
}

__global__ void chamfer_finalize_kernel(const float* __restrict__ acc,
                                        float* __restrict__ out)
{
    if (threadIdx.x == 0 && blockIdx.x == 0) {
        float total = 0.0f;
        #pragma unroll
        for (int i = 0; i < 16; ++i) total += powf(acc[i], 0.2f);
        *out = total * 0.125f;
    }
}

extern "C" void kernel_launch(void* const* d_in, const int* in_sizes, int n_in,
                              void* d_out, int out_size, void* d_ws, size_t ws_size,
                              hipStream_t stream)
{
    const float* x = (const float*)d_in[0];
    const float* y = (const float*)d_in[1];
    float* out = (float*)d_out;
    const int N = in_sizes[0] / 24;  // B=8, C=3
    const int M = in_sizes[1] / 24;

    const size_t needed = WS_TAB + (size_t)NQTOT * 8;  // ~528 KB

    if (N == 4096 && M == 4096 && ws_size >= needed) {
        unsigned char* ws = (unsigned char*)d_ws;
        float* acc = (float*)(ws + WS_ACC);
        unsigned int* fcnt = (unsigned int*)(ws + WS_FCNT);
        unsigned long long* tab = (unsigned long long*)(ws + WS_TAB);
        chamfer_scan_r8<<<NTILE * SPLITS, BQ, 0, stream>>>(x, y, tab, acc, fcnt);
        chamfer_gather_fin_r8<<<NQTOT / BQ, BQ, 0, stream>>>(x, y, tab, acc, fcnt, out);
    } else {
        // round-2 proven path
        unsigned char* ws = (unsigned char*)d_ws;
        float* acc = (float*)ws;
        unsigned long long* ptab = (unsigned long long*)(ws + 4096);
        const size_t nQ = (size_t)2 * 8 * N;
        hipMemsetAsync(acc, 0, 64, stream);
        hipMemsetAsync(ptab, 0xFF, nQ * 8, stream);
        chamfer_nn_split_kernel<<<(int)(nQ / BQ) * 4, BQ, 0, stream>>>(x, y, ptab, N, M);
        chamfer_gather_kernel<<<(int)(nQ / BQ), BQ, 0, stream>>>(x, y, ptab, acc, N, M);
        chamfer_finalize_kernel<<<1, 64, 0, stream>>>(acc, out);
    }
}